// Round 1
// baseline (10131.350 us; speedup 1.0000x reference)
//
#include <hip/hip_runtime.h>
#include <math.h>

#define TPQ 60
#define TPP 400
#define BB  16
#define II  256
#define HH  256

__device__ __forceinline__ float sigm(float x){ return 1.0f/(1.0f+__expf(-x)); }
__device__ __forceinline__ float tanhfast(float x){
  x = fminf(fmaxf(x,-20.0f),20.0f);
  float t = __expf(2.0f*x);
  return (t-1.0f)/(t+1.0f);
}

// dst[c*dstStride + dstOff + r] = src[r*C + c]
__global__ void transpose_k(float* __restrict__ dst, const float* __restrict__ src,
                            int R, int C, int dstStride, int dstOff){
  int idx = blockIdx.x*256 + threadIdx.x;
  if (idx >= R*C) return;
  int r = idx / C, c = idx % C;
  dst[(size_t)c*dstStride + dstOff + r] = src[idx];
}

// C[M][N] = A[M][K] @ B[K][N] (+bias[N]) ; EP==1: C = msrc * sigmoid(C)
// BM=BN=128, BK=8, 256 threads, 8x8 per thread. N%128==0, K%8==0 required; M guarded.
template<int EP>
__global__ __launch_bounds__(256) void gemm_f32(const float* __restrict__ A, const float* __restrict__ B,
    const float* __restrict__ bias, const float* __restrict__ msrc, float* __restrict__ C,
    int M, int N, int K)
{
  __shared__ float As[8][128];
  __shared__ float Bs[8][128];
  int tid = threadIdx.x;
  int m0 = blockIdx.y*128, n0 = blockIdx.x*128;
  int tx = tid & 15, ty = tid >> 4;
  float acc[8][8];
  #pragma unroll
  for (int i=0;i<8;i++)
    #pragma unroll
    for (int j=0;j<8;j++) acc[i][j] = 0.0f;

  int arow = tid >> 1, ak = (tid & 1)*4;
  int brow = tid >> 5, bcol = (tid & 31)*4;

  for (int k0=0;k0<K;k0+=8){
    float4 av;
    if (m0 + arow < M) av = *reinterpret_cast<const float4*>(&A[(size_t)(m0+arow)*K + k0 + ak]);
    else { av.x=0; av.y=0; av.z=0; av.w=0; }
    As[ak+0][arow]=av.x; As[ak+1][arow]=av.y; As[ak+2][arow]=av.z; As[ak+3][arow]=av.w;
    float4 bv = *reinterpret_cast<const float4*>(&B[(size_t)(k0+brow)*N + n0 + bcol]);
    *reinterpret_cast<float4*>(&Bs[brow][bcol]) = bv;
    __syncthreads();
    #pragma unroll
    for (int k=0;k<8;k++){
      float a[8], bb[8];
      *reinterpret_cast<float4*>(&a[0]) = *reinterpret_cast<const float4*>(&As[k][ty*8]);
      *reinterpret_cast<float4*>(&a[4]) = *reinterpret_cast<const float4*>(&As[k][ty*8+4]);
      *reinterpret_cast<float4*>(&bb[0]) = *reinterpret_cast<const float4*>(&Bs[k][tx*8]);
      *reinterpret_cast<float4*>(&bb[4]) = *reinterpret_cast<const float4*>(&Bs[k][tx*8+4]);
      #pragma unroll
      for (int i=0;i<8;i++)
        #pragma unroll
        for (int j=0;j<8;j++) acc[i][j] += a[i]*bb[j];
    }
    __syncthreads();
  }
  #pragma unroll
  for (int i=0;i<8;i++){
    int m = m0 + ty*8 + i;
    if (m >= M) continue;
    #pragma unroll
    for (int j=0;j<8;j++){
      int n = n0 + tx*8 + j;
      float val = acc[i][j];
      if (bias) val += bias[n];
      if (EP==1) val = msrc[(size_t)m*N + n] * sigm(val);
      C[(size_t)m*N + n] = val;
    }
  }
}

// one block per (p,b): scores over q (tanh attention), softmax over q, ct, concat write
__global__ __launch_bounds__(256) void attn_k(const float* __restrict__ Qh, const float* __restrict__ Ph,
   const float* __restrict__ qrep, const float* __restrict__ prep, const float* __restrict__ v,
   const float* __restrict__ qmask, float* __restrict__ xcat)
{
  int p = blockIdx.x, b = blockIdx.y;
  int tid = threadIdx.x;
  __shared__ float ph[HH];
  __shared__ float vv[HH];
  __shared__ float sc[64];
  size_t pb = (size_t)p*BB + b;
  ph[tid] = Ph[pb*HH + tid];
  vv[tid] = v[tid];
  xcat[pb*512 + tid] = prep[pb*II + tid];   // low half of concat = passage_repr
  __syncthreads();
  int wid = tid >> 6, lane = tid & 63;
  for (int q = wid; q < TPQ; q += 4){
    const float* qh = Qh + ((size_t)q*BB + b)*HH;
    float s = 0.0f;
    for (int hh = lane; hh < HH; hh += 64)
      s += vv[hh]*tanhfast(qh[hh] + ph[hh]);
    #pragma unroll
    for (int off=32; off>0; off>>=1) s += __shfl_xor(s, off);
    if (lane==0) sc[q] = s;
  }
  __syncthreads();
  if (wid==0){
    float m = (lane < TPQ) ? qmask[lane*BB + b] : 0.0f;
    float val = (lane < TPQ) ? (m*sc[lane] + (1.0f-m)*(-1e30f)) : -INFINITY;
    float mx = val;
    #pragma unroll
    for (int off=32; off>0; off>>=1) mx = fmaxf(mx, __shfl_xor(mx, off));
    float e = (lane < TPQ) ? __expf(val - mx) : 0.0f;
    float sum = e;
    #pragma unroll
    for (int off=32; off>0; off>>=1) sum += __shfl_xor(sum, off);
    if (lane < TPQ) sc[lane] = e / sum;
  }
  __syncthreads();
  float acc = 0.0f;
  for (int q=0;q<TPQ;q++)
    acc += sc[q] * qrep[((size_t)q*BB + b)*II + tid];
  xcat[pb*512 + 256 + tid] = acc;   // high half = ct
}

// 32 blocks: b = blockIdx&15, dir = blockIdx>>4. Thread j owns hidden index j (r,z,n rows).
// whhT: per (dir): [256 k][768 g] (pre-transposed). bhh: per dir 768.
__global__ __launch_bounds__(256) void gru_scan(const float* __restrict__ xg, const float* __restrict__ whhT,
     const float* __restrict__ bhh, float* __restrict__ out)
{
  int b   = blockIdx.x & 15;
  int dir = blockIdx.x >> 4;
  int j = threadIdx.x;
  __shared__ float h[HH];
  h[j] = 0.0f;
  __syncthreads();
  const float* w  = whhT + (size_t)dir*HH*768;
  const float* bh = bhh + dir*768;
  float b_r = bh[j], b_z = bh[256+j], b_n = bh[512+j];
  const float* wj = w + j;
  for (int s=0;s<TPP;s++){
    int t = dir ? (TPP-1-s) : s;
    float hr=b_r, hz=b_z, hn=b_n;
    for (int k=0;k<HH;k+=4){
      float4 h4 = *reinterpret_cast<const float4*>(&h[k]);
      const float* wr = wj + (size_t)k*768;
      hr += wr[0]*h4.x; hz += wr[256]*h4.x; hn += wr[512]*h4.x; wr += 768;
      hr += wr[0]*h4.y; hz += wr[256]*h4.y; hn += wr[512]*h4.y; wr += 768;
      hr += wr[0]*h4.z; hz += wr[256]*h4.z; hn += wr[512]*h4.z; wr += 768;
      hr += wr[0]*h4.w; hz += wr[256]*h4.w; hn += wr[512]*h4.w;
    }
    const float* xrow = xg + ((size_t)t*BB + b)*1536 + dir*768;
    float r = sigm(xrow[j]     + hr);
    float z = sigm(xrow[256+j] + hz);
    float n = tanhfast(xrow[512+j] + r*hn);
    float hold = h[j];
    float hnew = (1.0f - z)*n + z*hold;
    __syncthreads();
    h[j] = hnew;
    out[((size_t)t*BB + b)*512 + dir*HH + j] = hnew;
    __syncthreads();
  }
}

extern "C" void kernel_launch(void* const* d_in, const int* in_sizes, int n_in,
                              void* d_out, int out_size, void* d_ws, size_t ws_size,
                              hipStream_t stream)
{
  const float* prep  = (const float*)d_in[0];
  const float* qrep  = (const float*)d_in[1];
  const float* qmask = (const float*)d_in[3];
  const float* WuQ   = (const float*)d_in[4];
  const float* WuP   = (const float*)d_in[5];
  const float* v     = (const float*)d_in[6];
  const float* Wg    = (const float*)d_in[7];
  const float* Wih   = (const float*)d_in[8];
  const float* Whh   = (const float*)d_in[9];
  const float* bih   = (const float*)d_in[10];
  const float* bhh   = (const float*)d_in[11];
  float* out = (float*)d_out;

  float* ws = (float*)d_ws;
  size_t off = 0;
  float* WuQT = ws + off; off += 256*256;
  float* WuPT = ws + off; off += 256*256;
  float* WgT  = ws + off; off += 512*512;
  float* WihT = ws + off; off += (size_t)3*512*1536;      // per layer: [512][1536] (dir*768+g)
  float* WhhT = ws + off; off += (size_t)3*2*256*768;     // per (l,d): [256][768]
  float* Qh   = ws + off; off += (size_t)TPQ*BB*HH;
  float* Ph   = ws + off; off += (size_t)TPP*BB*HH;
  float* xcat = ws + off; off += (size_t)TPP*BB*512;
  float* ybuf = ws + off; off += (size_t)TPP*BB*512;
  float* xg   = ws + off; off += (size_t)TPP*BB*1536;

  auto T = [&](float* dst, const float* src, int R, int C, int st, int o){
    int n = R*C;
    transpose_k<<<dim3((n+255)/256), dim3(256), 0, stream>>>(dst, src, R, C, st, o);
  };
  T(WuQT, WuQ, 256,256,256,0);
  T(WuPT, WuP, 256,256,256,0);
  T(WgT,  Wg,  512,512,512,0);
  for (int l=0;l<3;l++)
    for (int d=0;d<2;d++){
      T(WihT + (size_t)l*512*1536, Wih + (size_t)(l*2+d)*768*512, 768, 512, 1536, d*768);
      T(WhhT + (size_t)(l*2+d)*256*768, Whh + (size_t)(l*2+d)*768*256, 768, 256, 768, 0);
    }

  // Qh = question @ WuQ.T : M=960, N=256, K=256
  gemm_f32<0><<<dim3(2, 8), dim3(256), 0, stream>>>(qrep, WuQT, nullptr, nullptr, Qh, TPQ*BB, 256, 256);
  // Ph = passage @ WuP.T : M=6400
  gemm_f32<0><<<dim3(2, 50), dim3(256), 0, stream>>>(prep, WuPT, nullptr, nullptr, Ph, TPP*BB, 256, 256);
  // attention + concat
  attn_k<<<dim3(TPP, BB), dim3(256), 0, stream>>>(Qh, Ph, qrep, prep, v, qmask, xcat);
  // gate: ybuf = xcat * sigmoid(xcat @ Wg.T)
  gemm_f32<1><<<dim3(4, 50), dim3(256), 0, stream>>>(xcat, WgT, nullptr, xcat, ybuf, TPP*BB, 512, 512);

  float* cur = ybuf;
  float* nxt = xcat;
  for (int l=0;l<3;l++){
    // xg = cur @ WihT[l] + bih[l]  : M=6400, N=1536, K=512
    gemm_f32<0><<<dim3(12, 50), dim3(256), 0, stream>>>(cur, WihT + (size_t)l*512*1536,
                                                        bih + (size_t)l*1536, nullptr, xg, TPP*BB, 1536, 512);
    float* o = (l==2) ? out : nxt;
    gru_scan<<<dim3(32), dim3(256), 0, stream>>>(xg, WhhT + (size_t)l*2*256*768, bhh + (size_t)l*2*768, o);
    float* tmp = cur; cur = o; nxt = tmp;
  }
}

// Round 3
// 5584.956 us; speedup vs baseline: 1.8140x; 1.8140x over previous
//
#include <hip/hip_runtime.h>
#include <math.h>

#define TPQ 60
#define TPP 400
#define BB  16
#define II  256
#define HH  256

typedef short bf16x8 __attribute__((ext_vector_type(8)));
typedef float f32x4  __attribute__((ext_vector_type(4)));

__device__ __forceinline__ float sigm(float x){ return 1.0f/(1.0f+__expf(-x)); }
__device__ __forceinline__ float tanhfast(float x){
  x = fminf(fmaxf(x,-20.0f),20.0f);
  float t = __expf(2.0f*x);
  return (t-1.0f)/(t+1.0f);
}
__device__ __forceinline__ short f2bf(float f){
  unsigned u = __float_as_uint(f);
  unsigned r = (u + 0x7fffu + ((u>>16)&1u)) >> 16;
  return (short)r;
}
__device__ __forceinline__ float bf2f(short h){
  return __uint_as_float(((unsigned)(unsigned short)h)<<16);
}

// dst[c*dstStride + dstOff + r] = src[r*C + c]
__global__ void transpose_k(float* __restrict__ dst, const float* __restrict__ src,
                            int R, int C, int dstStride, int dstOff){
  int idx = blockIdx.x*256 + threadIdx.x;
  if (idx >= R*C) return;
  int r = idx / C, c = idx % C;
  dst[(size_t)c*dstStride + dstOff + r] = src[idx];
}

// C[M][N] = A[M][K] @ B[K][N] (+bias[N]) ; EP==1: C = msrc * sigmoid(C)
template<int EP>
__global__ __launch_bounds__(256) void gemm_f32(const float* __restrict__ A, const float* __restrict__ B,
    const float* __restrict__ bias, const float* __restrict__ msrc, float* __restrict__ C,
    int M, int N, int K)
{
  __shared__ float As[8][128];
  __shared__ float Bs[8][128];
  int tid = threadIdx.x;
  int m0 = blockIdx.y*128, n0 = blockIdx.x*128;
  int tx = tid & 15, ty = tid >> 4;
  float acc[8][8];
  #pragma unroll
  for (int i=0;i<8;i++)
    #pragma unroll
    for (int j=0;j<8;j++) acc[i][j] = 0.0f;

  int arow = tid >> 1, ak = (tid & 1)*4;
  int brow = tid >> 5, bcol = (tid & 31)*4;

  for (int k0=0;k0<K;k0+=8){
    float4 av;
    if (m0 + arow < M) av = *reinterpret_cast<const float4*>(&A[(size_t)(m0+arow)*K + k0 + ak]);
    else { av.x=0; av.y=0; av.z=0; av.w=0; }
    As[ak+0][arow]=av.x; As[ak+1][arow]=av.y; As[ak+2][arow]=av.z; As[ak+3][arow]=av.w;
    float4 bv = *reinterpret_cast<const float4*>(&B[(size_t)(k0+brow)*N + n0 + bcol]);
    *reinterpret_cast<float4*>(&Bs[brow][bcol]) = bv;
    __syncthreads();
    #pragma unroll
    for (int k=0;k<8;k++){
      float a[8], bb[8];
      *reinterpret_cast<float4*>(&a[0]) = *reinterpret_cast<const float4*>(&As[k][ty*8]);
      *reinterpret_cast<float4*>(&a[4]) = *reinterpret_cast<const float4*>(&As[k][ty*8+4]);
      *reinterpret_cast<float4*>(&bb[0]) = *reinterpret_cast<const float4*>(&Bs[k][tx*8]);
      *reinterpret_cast<float4*>(&bb[4]) = *reinterpret_cast<const float4*>(&Bs[k][tx*8+4]);
      #pragma unroll
      for (int i=0;i<8;i++)
        #pragma unroll
        for (int j=0;j<8;j++) acc[i][j] += a[i]*bb[j];
    }
    __syncthreads();
  }
  #pragma unroll
  for (int i=0;i<8;i++){
    int m = m0 + ty*8 + i;
    if (m >= M) continue;
    #pragma unroll
    for (int j=0;j<8;j++){
      int n = n0 + tx*8 + j;
      float val = acc[i][j];
      if (bias) val += bias[n];
      if (EP==1) val = msrc[(size_t)m*N + n] * sigm(val);
      C[(size_t)m*N + n] = val;
    }
  }
}

// one block per (p,b): scores over q (tanh attention), softmax over q, ct, concat write
__global__ __launch_bounds__(256) void attn_k(const float* __restrict__ Qh, const float* __restrict__ Ph,
   const float* __restrict__ qrep, const float* __restrict__ prep, const float* __restrict__ v,
   const float* __restrict__ qmask, float* __restrict__ xcat)
{
  int p = blockIdx.x, b = blockIdx.y;
  int tid = threadIdx.x;
  __shared__ float ph[HH];
  __shared__ float vv[HH];
  __shared__ float sc[64];
  size_t pb = (size_t)p*BB + b;
  ph[tid] = Ph[pb*HH + tid];
  vv[tid] = v[tid];
  xcat[pb*512 + tid] = prep[pb*II + tid];
  __syncthreads();
  int wid = tid >> 6, lane = tid & 63;
  for (int q = wid; q < TPQ; q += 4){
    const float* qh = Qh + ((size_t)q*BB + b)*HH;
    float s = 0.0f;
    for (int hh = lane; hh < HH; hh += 64)
      s += vv[hh]*tanhfast(qh[hh] + ph[hh]);
    #pragma unroll
    for (int off=32; off>0; off>>=1) s += __shfl_xor(s, off);
    if (lane==0) sc[q] = s;
  }
  __syncthreads();
  if (wid==0){
    float m = (lane < TPQ) ? qmask[lane*BB + b] : 0.0f;
    float val = (lane < TPQ) ? (m*sc[lane] + (1.0f-m)*(-1e30f)) : -INFINITY;
    float mx = val;
    #pragma unroll
    for (int off=32; off>0; off>>=1) mx = fmaxf(mx, __shfl_xor(mx, off));
    float e = (lane < TPQ) ? __expf(val - mx) : 0.0f;
    float sum = e;
    #pragma unroll
    for (int off=32; off>0; off>>=1) sum += __shfl_xor(sum, off);
    if (lane < TPQ) sc[lane] = e / sum;
  }
  __syncthreads();
  float acc = 0.0f;
  for (int q=0;q<TPQ;q++)
    acc += sc[q] * qrep[((size_t)q*BB + b)*II + tid];
  xcat[pb*512 + 256 + tid] = acc;
}

// ---------------------------------------------------------------------------
// Persistent MFMA GRU scan. grid = 2 (dir), block = 512 (8 waves).
// Wave w owns hidden slice j in [w*32, w*32+32): gate rows gi*256 + w*32 + gg*16 + nl.
// Whh (bf16): ks 0..5 in registers (36 frags = 144 VGPR), ks 6..7 in LDS (96KB).
// h kept as hi/lo bf16 pair in swizzled LDS -> exact-f32 A operand via 2 MFMAs.
// ---------------------------------------------------------------------------
__global__ __launch_bounds__(512) void gru_scan_mfma(
    const float* __restrict__ xg,    // [TPP][16][1536], col = dir*768 + gate*256 + j
    const float* __restrict__ Whh,   // [2][768][256] (this layer)
    const float* __restrict__ bhh,   // [2][768]      (this layer)
    float* __restrict__ out)         // [TPP][16][512], col = dir*256 + j
{
  __shared__ unsigned short hhi[16*256];   // 8KB, swizzled: byte=(b*512+k*2)^((b&7)<<4)
  __shared__ unsigned short hlo[16*256];   // 8KB
  __shared__ short wlds[8*12*64*8];        // 96KB: wave x (ks-6)*6+tl x lane x 8

  const int dir  = blockIdx.x;
  const int tid  = threadIdx.x;
  const int wv   = tid >> 6;
  const int lane = tid & 63;
  const int nl   = lane & 15;       // N-col within tile / batch row for A
  const int kq   = lane >> 4;       // K-quarter selector

  // zero h
  for (int i = tid; i < 16*256; i += 512){ hhi[i] = 0; hlo[i] = 0; }

  // load Whh fragments as bf16. B[k][n] = Whh[nrow][k].
  // lane layout (16x16x32): n = lane&15, k = ks*32 + (lane>>4)*8 + e
  bf16x8 wreg[6][6];
  #pragma unroll
  for (int ks=0; ks<8; ks++){
    #pragma unroll
    for (int gg=0; gg<2; gg++){
      #pragma unroll
      for (int gi=0; gi<3; gi++){
        int tl = gg*3 + gi;
        int nrow = gi*256 + wv*32 + gg*16 + nl;
        const float* wsrc = Whh + (size_t)dir*768*256 + (size_t)nrow*256 + ks*32 + kq*8;
        bf16x8 f;
        #pragma unroll
        for (int e=0;e<8;e++) f[e] = f2bf(wsrc[e]);
        if (ks < 6) wreg[ks][tl] = f;
        else *reinterpret_cast<bf16x8*>(&wlds[((size_t)((wv*12 + (ks-6)*6 + tl)*64 + lane))*8]) = f;
      }
    }
  }

  // biases for this lane's columns
  float bias[2][3];
  #pragma unroll
  for (int gg=0; gg<2; gg++)
    #pragma unroll
    for (int gi=0; gi<3; gi++)
      bias[gg][gi] = bhh[dir*768 + gi*256 + wv*32 + gg*16 + nl];

  // lane's xg base: column = dir*768 + gi*256 + (wv*32 + gg*16 + nl)
  const float* xb = xg + dir*768 + wv*32 + nl;
  __syncthreads();

  #pragma unroll 1
  for (int s=0; s<TPP; s++){
    const int t = dir ? (TPP-1-s) : s;

    // issue xg loads early (latency hides under MFMA phase)
    float xv[2][3][4];
    size_t ro = (size_t)(t*16 + kq*4)*1536;
    #pragma unroll
    for (int gg=0; gg<2; gg++)
      #pragma unroll
      for (int gi=0; gi<3; gi++)
        #pragma unroll
        for (int mr=0; mr<4; mr++)
          xv[gg][gi][mr] = xb[ro + (size_t)mr*1536 + gi*256 + gg*16];

    // MFMA phase: acc[gg][gi] over K=256 (8 ksteps), hi+lo A operands
    f32x4 acc[2][3];
    #pragma unroll
    for (int gg=0; gg<2; gg++)
      #pragma unroll
      for (int gi=0; gi<3; gi++)
        acc[gg][gi] = (f32x4){0.f,0.f,0.f,0.f};

    const int abase = nl*512 + kq*16;
    const int aswz  = (nl&7)<<4;
    bf16x8 ah = *reinterpret_cast<const bf16x8*>((const char*)hhi + ((abase + 0*64) ^ aswz));
    bf16x8 al = *reinterpret_cast<const bf16x8*>((const char*)hlo + ((abase + 0*64) ^ aswz));
    #pragma unroll
    for (int ks=0; ks<8; ks++){
      bf16x8 ahn, aln;
      if (ks < 7){
        ahn = *reinterpret_cast<const bf16x8*>((const char*)hhi + ((abase + (ks+1)*64) ^ aswz));
        aln = *reinterpret_cast<const bf16x8*>((const char*)hlo + ((abase + (ks+1)*64) ^ aswz));
      }
      #pragma unroll
      for (int gg=0; gg<2; gg++){
        #pragma unroll
        for (int gi=0; gi<3; gi++){
          int tl = gg*3 + gi;
          bf16x8 w;
          if (ks < 6) w = wreg[ks][tl];
          else w = *reinterpret_cast<const bf16x8*>(&wlds[((size_t)((wv*12 + (ks-6)*6 + tl)*64 + lane))*8]);
          acc[gg][gi] = __builtin_amdgcn_mfma_f32_16x16x32_bf16(ah, w, acc[gg][gi], 0, 0, 0);
          acc[gg][gi] = __builtin_amdgcn_mfma_f32_16x16x32_bf16(al, w, acc[gg][gi], 0, 0, 0);
        }
      }
      ah = ahn; al = aln;
    }

    // epilogue: lane holds D col = nl (=j within group), rows m = kq*4 + mr
    float hnew[2][4];
    #pragma unroll
    for (int gg=0; gg<2; gg++){
      int jg = wv*32 + gg*16 + nl;
      #pragma unroll
      for (int mr=0; mr<4; mr++){
        int m = kq*4 + mr;
        int hbyte = (m*512 + jg*2) ^ ((m&7)<<4);
        float hold = bf2f(*(const short*)((const char*)hhi + hbyte))
                   + bf2f(*(const short*)((const char*)hlo + hbyte));
        float r = sigm(xv[gg][0][mr] + acc[gg][0][mr] + bias[gg][0]);
        float z = sigm(xv[gg][1][mr] + acc[gg][1][mr] + bias[gg][1]);
        float n = tanhfast(xv[gg][2][mr] + r*(acc[gg][2][mr] + bias[gg][2]));
        hnew[gg][mr] = (1.0f - z)*n + z*hold;
      }
    }

    __syncthreads();   // all waves done reading hhi/hlo for this step

    #pragma unroll
    for (int gg=0; gg<2; gg++){
      int jg = wv*32 + gg*16 + nl;
      #pragma unroll
      for (int mr=0; mr<4; mr++){
        int m = kq*4 + mr;
        float hv = hnew[gg][mr];
        short hi = f2bf(hv);
        short lo = f2bf(hv - bf2f(hi));
        int hbyte = (m*512 + jg*2) ^ ((m&7)<<4);
        *(short*)((char*)hhi + hbyte) = hi;
        *(short*)((char*)hlo + hbyte) = lo;
        out[(size_t)(t*16 + m)*512 + dir*256 + jg] = hv;
      }
    }
    __syncthreads();   // new h visible before next step's A reads
  }
}

extern "C" void kernel_launch(void* const* d_in, const int* in_sizes, int n_in,
                              void* d_out, int out_size, void* d_ws, size_t ws_size,
                              hipStream_t stream)
{
  const float* prep  = (const float*)d_in[0];
  const float* qrep  = (const float*)d_in[1];
  const float* qmask = (const float*)d_in[3];
  const float* WuQ   = (const float*)d_in[4];
  const float* WuP   = (const float*)d_in[5];
  const float* v     = (const float*)d_in[6];
  const float* Wg    = (const float*)d_in[7];
  const float* Wih   = (const float*)d_in[8];
  const float* Whh   = (const float*)d_in[9];
  const float* bih   = (const float*)d_in[10];
  const float* bhh   = (const float*)d_in[11];
  float* out = (float*)d_out;

  float* ws = (float*)d_ws;
  size_t off = 0;
  float* WuQT = ws + off; off += 256*256;
  float* WuPT = ws + off; off += 256*256;
  float* WgT  = ws + off; off += 512*512;
  float* WihT = ws + off; off += (size_t)3*512*1536;      // per layer: [512][1536] (dir*768+g)
  float* Qh   = ws + off; off += (size_t)TPQ*BB*HH;
  float* Ph   = ws + off; off += (size_t)TPP*BB*HH;
  float* xcat = ws + off; off += (size_t)TPP*BB*512;
  float* ybuf = ws + off; off += (size_t)TPP*BB*512;
  float* xg   = ws + off; off += (size_t)TPP*BB*1536;

  auto T = [&](float* dst, const float* src, int R, int C, int st, int o){
    int n = R*C;
    transpose_k<<<dim3((n+255)/256), dim3(256), 0, stream>>>(dst, src, R, C, st, o);
  };
  T(WuQT, WuQ, 256,256,256,0);
  T(WuPT, WuP, 256,256,256,0);
  T(WgT,  Wg,  512,512,512,0);
  for (int l=0;l<3;l++)
    for (int d=0;d<2;d++)
      T(WihT + (size_t)l*512*1536, Wih + (size_t)(l*2+d)*768*512, 768, 512, 1536, d*768);

  // Qh = question @ WuQ.T : M=960, N=256, K=256
  gemm_f32<0><<<dim3(2, 8), dim3(256), 0, stream>>>(qrep, WuQT, nullptr, nullptr, Qh, TPQ*BB, 256, 256);
  // Ph = passage @ WuP.T : M=6400
  gemm_f32<0><<<dim3(2, 50), dim3(256), 0, stream>>>(prep, WuPT, nullptr, nullptr, Ph, TPP*BB, 256, 256);
  // attention + concat
  attn_k<<<dim3(TPP, BB), dim3(256), 0, stream>>>(Qh, Ph, qrep, prep, v, qmask, xcat);
  // gate: ybuf = xcat * sigmoid(xcat @ Wg.T)
  gemm_f32<1><<<dim3(4, 50), dim3(256), 0, stream>>>(xcat, WgT, nullptr, xcat, ybuf, TPP*BB, 512, 512);

  float* cur = ybuf;
  float* nxt = xcat;
  for (int l=0;l<3;l++){
    // xg = cur @ WihT[l] + bih[l]  : M=6400, N=1536, K=512
    gemm_f32<0><<<dim3(12, 50), dim3(256), 0, stream>>>(cur, WihT + (size_t)l*512*1536,
                                                        bih + (size_t)l*1536, nullptr, xg, TPP*BB, 1536, 512);
    float* o = (l==2) ? out : nxt;
    gru_scan_mfma<<<dim3(2), dim3(512), 0, stream>>>(xg, Whh + (size_t)l*2*768*256,
                                                     bhh + (size_t)l*2*768, o);
    float* tmp = cur; cur = o; nxt = tmp;
  }
}

// Round 4
// 4129.195 us; speedup vs baseline: 2.4536x; 1.3526x over previous
//
#include <hip/hip_runtime.h>
#include <math.h>

#define TPQ 60
#define TPP 400
#define BB  16
#define II  256
#define HH  256

typedef short bf16x8 __attribute__((ext_vector_type(8)));
typedef float f32x4  __attribute__((ext_vector_type(4)));

__device__ __forceinline__ float sigm(float x){ return 1.0f/(1.0f+__expf(-x)); }
__device__ __forceinline__ float tanhfast(float x){
  x = fminf(fmaxf(x,-20.0f),20.0f);
  float t = __expf(2.0f*x);
  return (t-1.0f)/(t+1.0f);
}
__device__ __forceinline__ short f2bf(float f){
  unsigned u = __float_as_uint(f);
  unsigned r = (u + 0x7fffu + ((u>>16)&1u)) >> 16;
  return (short)r;
}
__device__ __forceinline__ float bf2f(short h){
  return __uint_as_float(((unsigned)(unsigned short)h)<<16);
}

// dst[c*dstStride + dstOff + r] = src[r*C + c]
__global__ void transpose_k(float* __restrict__ dst, const float* __restrict__ src,
                            int R, int C, int dstStride, int dstOff){
  int idx = blockIdx.x*256 + threadIdx.x;
  if (idx >= R*C) return;
  int r = idx / C, c = idx % C;
  dst[(size_t)c*dstStride + dstOff + r] = src[idx];
}

// C[M][N] = A[M][K] @ B[K][N] (+bias[N]) ; EP==1: C = msrc * sigmoid(C)
template<int EP>
__global__ __launch_bounds__(256) void gemm_f32(const float* __restrict__ A, const float* __restrict__ B,
    const float* __restrict__ bias, const float* __restrict__ msrc, float* __restrict__ C,
    int M, int N, int K)
{
  __shared__ float As[8][128];
  __shared__ float Bs[8][128];
  int tid = threadIdx.x;
  int m0 = blockIdx.y*128, n0 = blockIdx.x*128;
  int tx = tid & 15, ty = tid >> 4;
  float acc[8][8];
  #pragma unroll
  for (int i=0;i<8;i++)
    #pragma unroll
    for (int j=0;j<8;j++) acc[i][j] = 0.0f;

  int arow = tid >> 1, ak = (tid & 1)*4;
  int brow = tid >> 5, bcol = (tid & 31)*4;

  for (int k0=0;k0<K;k0+=8){
    float4 av;
    if (m0 + arow < M) av = *reinterpret_cast<const float4*>(&A[(size_t)(m0+arow)*K + k0 + ak]);
    else { av.x=0; av.y=0; av.z=0; av.w=0; }
    As[ak+0][arow]=av.x; As[ak+1][arow]=av.y; As[ak+2][arow]=av.z; As[ak+3][arow]=av.w;
    float4 bv = *reinterpret_cast<const float4*>(&B[(size_t)(k0+brow)*N + n0 + bcol]);
    *reinterpret_cast<float4*>(&Bs[brow][bcol]) = bv;
    __syncthreads();
    #pragma unroll
    for (int k=0;k<8;k++){
      float a[8], bb[8];
      *reinterpret_cast<float4*>(&a[0]) = *reinterpret_cast<const float4*>(&As[k][ty*8]);
      *reinterpret_cast<float4*>(&a[4]) = *reinterpret_cast<const float4*>(&As[k][ty*8+4]);
      *reinterpret_cast<float4*>(&bb[0]) = *reinterpret_cast<const float4*>(&Bs[k][tx*8]);
      *reinterpret_cast<float4*>(&bb[4]) = *reinterpret_cast<const float4*>(&Bs[k][tx*8+4]);
      #pragma unroll
      for (int i=0;i<8;i++)
        #pragma unroll
        for (int j=0;j<8;j++) acc[i][j] += a[i]*bb[j];
    }
    __syncthreads();
  }
  #pragma unroll
  for (int i=0;i<8;i++){
    int m = m0 + ty*8 + i;
    if (m >= M) continue;
    #pragma unroll
    for (int j=0;j<8;j++){
      int n = n0 + tx*8 + j;
      float val = acc[i][j];
      if (bias) val += bias[n];
      if (EP==1) val = msrc[(size_t)m*N + n] * sigm(val);
      C[(size_t)m*N + n] = val;
    }
  }
}

// one block per (p,b): scores over q (tanh attention), softmax over q, ct, concat write
__global__ __launch_bounds__(256) void attn_k(const float* __restrict__ Qh, const float* __restrict__ Ph,
   const float* __restrict__ qrep, const float* __restrict__ prep, const float* __restrict__ v,
   const float* __restrict__ qmask, float* __restrict__ xcat)
{
  int p = blockIdx.x, b = blockIdx.y;
  int tid = threadIdx.x;
  __shared__ float ph[HH];
  __shared__ float vv[HH];
  __shared__ float sc[64];
  size_t pb = (size_t)p*BB + b;
  ph[tid] = Ph[pb*HH + tid];
  vv[tid] = v[tid];
  xcat[pb*512 + tid] = prep[pb*II + tid];
  __syncthreads();
  int wid = tid >> 6, lane = tid & 63;
  for (int q = wid; q < TPQ; q += 4){
    const float* qh = Qh + ((size_t)q*BB + b)*HH;
    float s = 0.0f;
    for (int hh = lane; hh < HH; hh += 64)
      s += vv[hh]*tanhfast(qh[hh] + ph[hh]);
    #pragma unroll
    for (int off=32; off>0; off>>=1) s += __shfl_xor(s, off);
    if (lane==0) sc[q] = s;
  }
  __syncthreads();
  if (wid==0){
    float m = (lane < TPQ) ? qmask[lane*BB + b] : 0.0f;
    float val = (lane < TPQ) ? (m*sc[lane] + (1.0f-m)*(-1e30f)) : -INFINITY;
    float mx = val;
    #pragma unroll
    for (int off=32; off>0; off>>=1) mx = fmaxf(mx, __shfl_xor(mx, off));
    float e = (lane < TPQ) ? __expf(val - mx) : 0.0f;
    float sum = e;
    #pragma unroll
    for (int off=32; off>0; off>>=1) sum += __shfl_xor(sum, off);
    if (lane < TPQ) sc[lane] = e / sum;
  }
  __syncthreads();
  float acc = 0.0f;
  for (int q=0;q<TPQ;q++)
    acc += sc[q] * qrep[((size_t)q*BB + b)*II + tid];
  xcat[pb*512 + 256 + tid] = acc;
}

// ---------------------------------------------------------------------------
// Persistent MFMA GRU scan v2. grid = 2 (dir), block = 512 (8 waves).
// Wave w owns hidden slice [w*32, w*32+32): gate rows gi*256 + w*32 + gg*16 + nl.
// Whh bf16: ks 0..5 in registers (36 frags), ks 6..7 in LDS (96KB, read batched).
// h: SINGLE bf16 in ping-pong swizzled LDS (A operand); exact f32 carry ("hold")
// lives in registers (each lane re-reads only what it wrote). 1 barrier/step.
// ---------------------------------------------------------------------------
__global__ __launch_bounds__(512) void gru_scan_mfma(
    const float* __restrict__ xg,    // [TPP][16][1536], col = dir*768 + gate*256 + j
    const float* __restrict__ Whh,   // [2][768][256] (this layer)
    const float* __restrict__ bhh,   // [2][768]      (this layer)
    float* __restrict__ out)         // [TPP][16][512], col = dir*256 + j
{
  __shared__ unsigned short hh[2][16*256]; // 2x8KB ping-pong, swizzled: byte=(b*512+k*2)^((b&7)<<4)
  __shared__ short wlds[8*12*64*8];        // 96KB: wave x ((ks-6)*6+tl) x lane x 8

  const int dir  = blockIdx.x;
  const int tid  = threadIdx.x;
  const int wv   = tid >> 6;
  const int lane = tid & 63;
  const int nl   = lane & 15;       // A row (batch) / B,D col
  const int kq   = lane >> 4;       // K-quarter / D row-quad

  for (int i = tid; i < 2*16*256; i += 512) ((unsigned short*)hh)[i] = 0;

  // load Whh fragments as bf16. B[k][n] = Whh[nrow][k].
  // lane layout (16x16x32): n = lane&15, k = ks*32 + (lane>>4)*8 + e
  bf16x8 wreg[6][6];
  #pragma unroll
  for (int ks=0; ks<8; ks++){
    #pragma unroll
    for (int gg=0; gg<2; gg++){
      #pragma unroll
      for (int gi=0; gi<3; gi++){
        int tl = gg*3 + gi;
        int nrow = gi*256 + wv*32 + gg*16 + nl;
        const float* wsrc = Whh + (size_t)dir*768*256 + (size_t)nrow*256 + ks*32 + kq*8;
        bf16x8 f;
        #pragma unroll
        for (int e=0;e<8;e++) f[e] = f2bf(wsrc[e]);
        if (ks < 6) wreg[ks][tl] = f;
        else *reinterpret_cast<bf16x8*>(&wlds[((size_t)((wv*12 + (ks-6)*6 + tl)*64 + lane))*8]) = f;
      }
    }
  }

  float bias[2][3];
  #pragma unroll
  for (int gg=0; gg<2; gg++)
    #pragma unroll
    for (int gi=0; gi<3; gi++)
      bias[gg][gi] = bhh[dir*768 + gi*256 + wv*32 + gg*16 + nl];

  // lane's xg base: column = dir*768 + gi*256 + (wv*32 + gg*16 + nl)
  const float* xb = xg + dir*768 + wv*32 + nl;

  float hold[2][4];
  #pragma unroll
  for (int gg=0; gg<2; gg++)
    #pragma unroll
    for (int mr=0; mr<4; mr++) hold[gg][mr] = 0.0f;

  const int abase = nl*512 + kq*16;
  const int aswz  = (nl&7)<<4;

  __syncthreads();

  #pragma unroll 1
  for (int s=0; s<TPP; s++){
    const int t = dir ? (TPP-1-s) : s;

    // issue xg loads early (latency hides under MFMA phase)
    float xv[2][3][4];
    size_t ro = (size_t)(t*16 + kq*4)*1536;
    #pragma unroll
    for (int gg=0; gg<2; gg++)
      #pragma unroll
      for (int gi=0; gi<3; gi++)
        #pragma unroll
        for (int mr=0; mr<4; mr++)
          xv[gg][gi][mr] = xb[ro + (size_t)mr*1536 + gi*256 + gg*16];

    f32x4 acc[2][3];
    #pragma unroll
    for (int gg=0; gg<2; gg++)
      #pragma unroll
      for (int gi=0; gi<3; gi++)
        acc[gg][gi] = (f32x4){0.f,0.f,0.f,0.f};

    const char* hbase = (const char*)hh[s&1];

    // ---- phase 1: ks 6,7 (weights from LDS, reads batched up-front) ----
    bf16x8 a6 = *reinterpret_cast<const bf16x8*>(hbase + ((abase + 6*64) ^ aswz));
    bf16x8 a7 = *reinterpret_cast<const bf16x8*>(hbase + ((abase + 7*64) ^ aswz));
    bf16x8 w6[6], w7[6];
    #pragma unroll
    for (int tl=0; tl<6; tl++)
      w6[tl] = *reinterpret_cast<const bf16x8*>(&wlds[((size_t)((wv*12 + 0*6 + tl)*64 + lane))*8]);
    #pragma unroll
    for (int tl=0; tl<6; tl++)
      w7[tl] = *reinterpret_cast<const bf16x8*>(&wlds[((size_t)((wv*12 + 1*6 + tl)*64 + lane))*8]);
    #pragma unroll
    for (int gg=0; gg<2; gg++)
      #pragma unroll
      for (int gi=0; gi<3; gi++)
        acc[gg][gi] = __builtin_amdgcn_mfma_f32_16x16x32_bf16(a6, w6[gg*3+gi], acc[gg][gi], 0, 0, 0);
    #pragma unroll
    for (int gg=0; gg<2; gg++)
      #pragma unroll
      for (int gi=0; gi<3; gi++)
        acc[gg][gi] = __builtin_amdgcn_mfma_f32_16x16x32_bf16(a7, w7[gg*3+gi], acc[gg][gi], 0, 0, 0);

    // ---- phase 2: ks 0..5 (weights in registers, A prefetched) ----
    bf16x8 ah = *reinterpret_cast<const bf16x8*>(hbase + ((abase + 0*64) ^ aswz));
    #pragma unroll
    for (int ks=0; ks<6; ks++){
      bf16x8 ahn;
      if (ks < 5)
        ahn = *reinterpret_cast<const bf16x8*>(hbase + ((abase + (ks+1)*64) ^ aswz));
      #pragma unroll
      for (int gg=0; gg<2; gg++)
        #pragma unroll
        for (int gi=0; gi<3; gi++)
          acc[gg][gi] = __builtin_amdgcn_mfma_f32_16x16x32_bf16(ah, wreg[ks][gg*3+gi], acc[gg][gi], 0, 0, 0);
      if (ks < 5) ah = ahn;
    }

    // ---- epilogue: gates; hold is in registers ----
    char* wb = (char*)hh[(s&1)^1];
    #pragma unroll
    for (int gg=0; gg<2; gg++){
      int jg = wv*32 + gg*16 + nl;
      #pragma unroll
      for (int mr=0; mr<4; mr++){
        int m = kq*4 + mr;
        float r = sigm(xv[gg][0][mr] + acc[gg][0][mr] + bias[gg][0]);
        float z = sigm(xv[gg][1][mr] + acc[gg][1][mr] + bias[gg][1]);
        float n = tanhfast(xv[gg][2][mr] + r*(acc[gg][2][mr] + bias[gg][2]));
        float hv = (1.0f - z)*n + z*hold[gg][mr];
        hold[gg][mr] = hv;
        int hbyte = (m*512 + jg*2) ^ ((m&7)<<4);
        *(short*)(wb + hbyte) = f2bf(hv);
        out[(size_t)(t*16 + m)*512 + dir*256 + jg] = hv;
      }
    }
    __syncthreads();   // new h (buf 1-p) visible before next step's A reads
  }
}

extern "C" void kernel_launch(void* const* d_in, const int* in_sizes, int n_in,
                              void* d_out, int out_size, void* d_ws, size_t ws_size,
                              hipStream_t stream)
{
  const float* prep  = (const float*)d_in[0];
  const float* qrep  = (const float*)d_in[1];
  const float* qmask = (const float*)d_in[3];
  const float* WuQ   = (const float*)d_in[4];
  const float* WuP   = (const float*)d_in[5];
  const float* v     = (const float*)d_in[6];
  const float* Wg    = (const float*)d_in[7];
  const float* Wih   = (const float*)d_in[8];
  const float* Whh   = (const float*)d_in[9];
  const float* bih   = (const float*)d_in[10];
  const float* bhh   = (const float*)d_in[11];
  float* out = (float*)d_out;

  float* ws = (float*)d_ws;
  size_t off = 0;
  float* WuQT = ws + off; off += 256*256;
  float* WuPT = ws + off; off += 256*256;
  float* WgT  = ws + off; off += 512*512;
  float* WihT = ws + off; off += (size_t)3*512*1536;      // per layer: [512][1536] (dir*768+g)
  float* Qh   = ws + off; off += (size_t)TPQ*BB*HH;
  float* Ph   = ws + off; off += (size_t)TPP*BB*HH;
  float* xcat = ws + off; off += (size_t)TPP*BB*512;
  float* ybuf = ws + off; off += (size_t)TPP*BB*512;
  float* xg   = ws + off; off += (size_t)TPP*BB*1536;

  auto T = [&](float* dst, const float* src, int R, int C, int st, int o){
    int n = R*C;
    transpose_k<<<dim3((n+255)/256), dim3(256), 0, stream>>>(dst, src, R, C, st, o);
  };
  T(WuQT, WuQ, 256,256,256,0);
  T(WuPT, WuP, 256,256,256,0);
  T(WgT,  Wg,  512,512,512,0);
  for (int l=0;l<3;l++)
    for (int d=0;d<2;d++)
      T(WihT + (size_t)l*512*1536, Wih + (size_t)(l*2+d)*768*512, 768, 512, 1536, d*768);

  // Qh = question @ WuQ.T : M=960, N=256, K=256
  gemm_f32<0><<<dim3(2, 8), dim3(256), 0, stream>>>(qrep, WuQT, nullptr, nullptr, Qh, TPQ*BB, 256, 256);
  // Ph = passage @ WuP.T : M=6400
  gemm_f32<0><<<dim3(2, 50), dim3(256), 0, stream>>>(prep, WuPT, nullptr, nullptr, Ph, TPP*BB, 256, 256);
  // attention + concat
  attn_k<<<dim3(TPP, BB), dim3(256), 0, stream>>>(Qh, Ph, qrep, prep, v, qmask, xcat);
  // gate: ybuf = xcat * sigmoid(xcat @ Wg.T)
  gemm_f32<1><<<dim3(4, 50), dim3(256), 0, stream>>>(xcat, WgT, nullptr, xcat, ybuf, TPP*BB, 512, 512);

  float* cur = ybuf;
  float* nxt = xcat;
  for (int l=0;l<3;l++){
    // xg = cur @ WihT[l] + bih[l]  : M=6400, N=1536, K=512
    gemm_f32<0><<<dim3(12, 50), dim3(256), 0, stream>>>(cur, WihT + (size_t)l*512*1536,
                                                        bih + (size_t)l*1536, nullptr, xg, TPP*BB, 1536, 512);
    float* o = (l==2) ? out : nxt;
    gru_scan_mfma<<<dim3(2), dim3(512), 0, stream>>>(xg, Whh + (size_t)l*2*768*256,
                                                     bhh + (size_t)l*2*768, o);
    float* tmp = cur; cur = o; nxt = tmp;
  }
}

// Round 5
// 2702.723 us; speedup vs baseline: 3.7486x; 1.5278x over previous
//
#include <hip/hip_runtime.h>
#include <math.h>

#define TPQ 60
#define TPP 400
#define BB  16
#define II  256
#define HH  256

typedef short bf16x8 __attribute__((ext_vector_type(8)));
typedef float f32x4  __attribute__((ext_vector_type(4)));

__device__ __forceinline__ float sigm(float x){ return 1.0f/(1.0f+__expf(-x)); }
__device__ __forceinline__ float tanhfast(float x){
  x = fminf(fmaxf(x,-20.0f),20.0f);
  float t = __expf(2.0f*x);
  return (t-1.0f)/(t+1.0f);
}
__device__ __forceinline__ short f2bf(float f){
  unsigned u = __float_as_uint(f);
  unsigned r = (u + 0x7fffu + ((u>>16)&1u)) >> 16;
  return (short)r;
}
__device__ __forceinline__ float bf2f(short h){
  return __uint_as_float(((unsigned)(unsigned short)h)<<16);
}

// dst[c*dstStride + dstOff + r] = src[r*C + c]
__global__ void transpose_k(float* __restrict__ dst, const float* __restrict__ src,
                            int R, int C, int dstStride, int dstOff){
  int idx = blockIdx.x*256 + threadIdx.x;
  if (idx >= R*C) return;
  int r = idx / C, c = idx % C;
  dst[(size_t)c*dstStride + dstOff + r] = src[idx];
}

// C[M][N] = A[M][K] @ B[K][N] (+bias[N]) ; EP==1: C = msrc * sigmoid(C)
template<int EP>
__global__ __launch_bounds__(256) void gemm_f32(const float* __restrict__ A, const float* __restrict__ B,
    const float* __restrict__ bias, const float* __restrict__ msrc, float* __restrict__ C,
    int M, int N, int K)
{
  __shared__ float As[8][128];
  __shared__ float Bs[8][128];
  int tid = threadIdx.x;
  int m0 = blockIdx.y*128, n0 = blockIdx.x*128;
  int tx = tid & 15, ty = tid >> 4;
  float acc[8][8];
  #pragma unroll
  for (int i=0;i<8;i++)
    #pragma unroll
    for (int j=0;j<8;j++) acc[i][j] = 0.0f;

  int arow = tid >> 1, ak = (tid & 1)*4;
  int brow = tid >> 5, bcol = (tid & 31)*4;

  for (int k0=0;k0<K;k0+=8){
    float4 av;
    if (m0 + arow < M) av = *reinterpret_cast<const float4*>(&A[(size_t)(m0+arow)*K + k0 + ak]);
    else { av.x=0; av.y=0; av.z=0; av.w=0; }
    As[ak+0][arow]=av.x; As[ak+1][arow]=av.y; As[ak+2][arow]=av.z; As[ak+3][arow]=av.w;
    float4 bv = *reinterpret_cast<const float4*>(&B[(size_t)(k0+brow)*N + n0 + bcol]);
    *reinterpret_cast<float4*>(&Bs[brow][bcol]) = bv;
    __syncthreads();
    #pragma unroll
    for (int k=0;k<8;k++){
      float a[8], bb[8];
      *reinterpret_cast<float4*>(&a[0]) = *reinterpret_cast<const float4*>(&As[k][ty*8]);
      *reinterpret_cast<float4*>(&a[4]) = *reinterpret_cast<const float4*>(&As[k][ty*8+4]);
      *reinterpret_cast<float4*>(&bb[0]) = *reinterpret_cast<const float4*>(&Bs[k][tx*8]);
      *reinterpret_cast<float4*>(&bb[4]) = *reinterpret_cast<const float4*>(&Bs[k][tx*8+4]);
      #pragma unroll
      for (int i=0;i<8;i++)
        #pragma unroll
        for (int j=0;j<8;j++) acc[i][j] += a[i]*bb[j];
    }
    __syncthreads();
  }
  #pragma unroll
  for (int i=0;i<8;i++){
    int m = m0 + ty*8 + i;
    if (m >= M) continue;
    #pragma unroll
    for (int j=0;j<8;j++){
      int n = n0 + tx*8 + j;
      float val = acc[i][j];
      if (bias) val += bias[n];
      if (EP==1) val = msrc[(size_t)m*N + n] * sigm(val);
      C[(size_t)m*N + n] = val;
    }
  }
}

// one block per (p,b): scores over q (tanh attention), softmax over q, ct, concat write
__global__ __launch_bounds__(256) void attn_k(const float* __restrict__ Qh, const float* __restrict__ Ph,
   const float* __restrict__ qrep, const float* __restrict__ prep, const float* __restrict__ v,
   const float* __restrict__ qmask, float* __restrict__ xcat)
{
  int p = blockIdx.x, b = blockIdx.y;
  int tid = threadIdx.x;
  __shared__ float ph[HH];
  __shared__ float vv[HH];
  __shared__ float sc[64];
  size_t pb = (size_t)p*BB + b;
  ph[tid] = Ph[pb*HH + tid];
  vv[tid] = v[tid];
  xcat[pb*512 + tid] = prep[pb*II + tid];
  __syncthreads();
  int wid = tid >> 6, lane = tid & 63;
  for (int q = wid; q < TPQ; q += 4){
    const float* qh = Qh + ((size_t)q*BB + b)*HH;
    float s = 0.0f;
    for (int hh = lane; hh < HH; hh += 64)
      s += vv[hh]*tanhfast(qh[hh] + ph[hh]);
    #pragma unroll
    for (int off=32; off>0; off>>=1) s += __shfl_xor(s, off);
    if (lane==0) sc[q] = s;
  }
  __syncthreads();
  if (wid==0){
    float m = (lane < TPQ) ? qmask[lane*BB + b] : 0.0f;
    float val = (lane < TPQ) ? (m*sc[lane] + (1.0f-m)*(-1e30f)) : -INFINITY;
    float mx = val;
    #pragma unroll
    for (int off=32; off>0; off>>=1) mx = fmaxf(mx, __shfl_xor(mx, off));
    float e = (lane < TPQ) ? __expf(val - mx) : 0.0f;
    float sum = e;
    #pragma unroll
    for (int off=32; off>0; off>>=1) sum += __shfl_xor(sum, off);
    if (lane < TPQ) sc[lane] = e / sum;
  }
  __syncthreads();
  float acc = 0.0f;
  for (int q=0;q<TPQ;q++)
    acc += sc[q] * qrep[((size_t)q*BB + b)*II + tid];
  xcat[pb*512 + 256 + tid] = acc;
}

// ---------------------------------------------------------------------------
// Persistent MFMA GRU scan v3: chain-parallel. grid = 32 (b,dir), block = 512.
// Each block owns ONE (batch, dir) chain. Full Whh (bf16) in registers:
// wave w owns gate rows gi*256 + w*32 + gg*16 + nl  -> 48 frags = 192 VGPR.
// h: 256 bf16 in ping-pong LDS (512B x2), read as broadcast A-frags (M=1,
// only D-row 0 used). f32 carry in lane registers. 1 barrier/step.
// ---------------------------------------------------------------------------
__global__ __launch_bounds__(512) void gru_scan_mfma(
    const float* __restrict__ xg,    // [TPP][16][1536], col = dir*768 + gate*256 + j
    const float* __restrict__ Whh,   // [2][768][256] (this layer)
    const float* __restrict__ bhh,   // [2][768]      (this layer)
    float* __restrict__ out)         // [TPP][16][512], col = dir*256 + j
{
  __shared__ unsigned short hbuf[2][256];  // ping-pong bf16 h

  const int b   = blockIdx.x & 15;
  const int dir = blockIdx.x >> 4;
  const int tid  = threadIdx.x;
  const int wv   = tid >> 6;
  const int lane = tid & 63;
  const int nl   = lane & 15;       // A row (only 0 used) / B,D col
  const int kq   = lane >> 4;       // K sub-slice

  ((unsigned short*)hbuf)[tid] = 0;  // 512 entries, 512 threads

  // Whh fragments bf16, all in registers. B[k][n] = Whh[nrow][k].
  // 16x16x32 B lane layout: n = lane&15, k = ks*32 + kq*8 + e
  bf16x8 wreg[8][6];
  #pragma unroll
  for (int ks=0; ks<8; ks++){
    #pragma unroll
    for (int gg=0; gg<2; gg++){
      #pragma unroll
      for (int gi=0; gi<3; gi++){
        int nrow = gi*256 + wv*32 + gg*16 + nl;
        const float* wsrc = Whh + (size_t)dir*768*256 + (size_t)nrow*256 + ks*32 + kq*8;
        float4 lo = *reinterpret_cast<const float4*>(wsrc);
        float4 hi = *reinterpret_cast<const float4*>(wsrc+4);
        bf16x8 f;
        f[0]=f2bf(lo.x); f[1]=f2bf(lo.y); f[2]=f2bf(lo.z); f[3]=f2bf(lo.w);
        f[4]=f2bf(hi.x); f[5]=f2bf(hi.y); f[6]=f2bf(hi.z); f[7]=f2bf(hi.w);
        wreg[ks][gg*3+gi] = f;
      }
    }
  }

  float bias[2][3];
  #pragma unroll
  for (int gg=0; gg<2; gg++)
    #pragma unroll
    for (int gi=0; gi<3; gi++)
      bias[gg][gi] = bhh[dir*768 + gi*256 + wv*32 + gg*16 + nl];

  // lane's xg column base: dir*768 + gi*256 + (wv*32 + gg*16 + nl)
  const float* xb = xg + dir*768 + wv*32 + nl;

  float hold[2] = {0.0f, 0.0f};

  __syncthreads();

  #pragma unroll 1
  for (int s=0; s<TPP; s++){
    const int t = dir ? (TPP-1-s) : s;

    // xg values for this step (consumed in epilogue; latency hides under MFMA)
    float xv[2][3];
    {
      size_t ro = (size_t)(t*16 + b)*1536;
      #pragma unroll
      for (int gg=0; gg<2; gg++)
        #pragma unroll
        for (int gi=0; gi<3; gi++)
          xv[gg][gi] = xb[ro + gi*256 + gg*16];
    }

    f32x4 acc[2][3];
    #pragma unroll
    for (int gg=0; gg<2; gg++)
      #pragma unroll
      for (int gi=0; gi<3; gi++)
        acc[gg][gi] = (f32x4){0.f,0.f,0.f,0.f};

    // A frags: broadcast h (bf16). byte addr = ks*64 + kq*16, independent of nl.
    const char* hp = (const char*)hbuf[s&1];
    bf16x8 a = *reinterpret_cast<const bf16x8*>(hp + kq*16);
    #pragma unroll
    for (int ks=0; ks<8; ks++){
      bf16x8 an;
      if (ks < 7)
        an = *reinterpret_cast<const bf16x8*>(hp + (ks+1)*64 + kq*16);
      #pragma unroll
      for (int gg=0; gg<2; gg++)
        #pragma unroll
        for (int gi=0; gi<3; gi++)
          acc[gg][gi] = __builtin_amdgcn_mfma_f32_16x16x32_bf16(a, wreg[ks][gg*3+gi], acc[gg][gi], 0, 0, 0);
      if (ks < 7) a = an;
    }

    // epilogue: D row 0 lives in lanes 0..15, reg 0
    if (lane < 16){
      unsigned short* wb = hbuf[(s&1)^1];
      #pragma unroll
      for (int gg=0; gg<2; gg++){
        int j = wv*32 + gg*16 + nl;
        float r = sigm(xv[gg][0] + acc[gg][0][0] + bias[gg][0]);
        float z = sigm(xv[gg][1] + acc[gg][1][0] + bias[gg][1]);
        float n = tanhfast(xv[gg][2] + r*(acc[gg][2][0] + bias[gg][2]));
        float hv = (1.0f - z)*n + z*hold[gg];
        hold[gg] = hv;
        wb[j] = (unsigned short)f2bf(hv);
        out[(size_t)(t*16 + b)*512 + dir*256 + j] = hv;
      }
    }
    __syncthreads();   // new h visible before next step's A reads
  }
}

extern "C" void kernel_launch(void* const* d_in, const int* in_sizes, int n_in,
                              void* d_out, int out_size, void* d_ws, size_t ws_size,
                              hipStream_t stream)
{
  const float* prep  = (const float*)d_in[0];
  const float* qrep  = (const float*)d_in[1];
  const float* qmask = (const float*)d_in[3];
  const float* WuQ   = (const float*)d_in[4];
  const float* WuP   = (const float*)d_in[5];
  const float* v     = (const float*)d_in[6];
  const float* Wg    = (const float*)d_in[7];
  const float* Wih   = (const float*)d_in[8];
  const float* Whh   = (const float*)d_in[9];
  const float* bih   = (const float*)d_in[10];
  const float* bhh   = (const float*)d_in[11];
  float* out = (float*)d_out;

  float* ws = (float*)d_ws;
  size_t off = 0;
  float* WuQT = ws + off; off += 256*256;
  float* WuPT = ws + off; off += 256*256;
  float* WgT  = ws + off; off += 512*512;
  float* WihT = ws + off; off += (size_t)3*512*1536;      // per layer: [512][1536] (dir*768+g)
  float* Qh   = ws + off; off += (size_t)TPQ*BB*HH;
  float* Ph   = ws + off; off += (size_t)TPP*BB*HH;
  float* xcat = ws + off; off += (size_t)TPP*BB*512;
  float* ybuf = ws + off; off += (size_t)TPP*BB*512;
  float* xg   = ws + off; off += (size_t)TPP*BB*1536;

  auto T = [&](float* dst, const float* src, int R, int C, int st, int o){
    int n = R*C;
    transpose_k<<<dim3((n+255)/256), dim3(256), 0, stream>>>(dst, src, R, C, st, o);
  };
  T(WuQT, WuQ, 256,256,256,0);
  T(WuPT, WuP, 256,256,256,0);
  T(WgT,  Wg,  512,512,512,0);
  for (int l=0;l<3;l++)
    for (int d=0;d<2;d++)
      T(WihT + (size_t)l*512*1536, Wih + (size_t)(l*2+d)*768*512, 768, 512, 1536, d*768);

  // Qh = question @ WuQ.T : M=960, N=256, K=256
  gemm_f32<0><<<dim3(2, 8), dim3(256), 0, stream>>>(qrep, WuQT, nullptr, nullptr, Qh, TPQ*BB, 256, 256);
  // Ph = passage @ WuP.T : M=6400
  gemm_f32<0><<<dim3(2, 50), dim3(256), 0, stream>>>(prep, WuPT, nullptr, nullptr, Ph, TPP*BB, 256, 256);
  // attention + concat
  attn_k<<<dim3(TPP, BB), dim3(256), 0, stream>>>(Qh, Ph, qrep, prep, v, qmask, xcat);
  // gate: ybuf = xcat * sigmoid(xcat @ Wg.T)
  gemm_f32<1><<<dim3(4, 50), dim3(256), 0, stream>>>(xcat, WgT, nullptr, xcat, ybuf, TPP*BB, 512, 512);

  float* cur = ybuf;
  float* nxt = xcat;
  for (int l=0;l<3;l++){
    // xg = cur @ WihT[l] + bih[l]  : M=6400, N=1536, K=512
    gemm_f32<0><<<dim3(12, 50), dim3(256), 0, stream>>>(cur, WihT + (size_t)l*512*1536,
                                                        bih + (size_t)l*1536, nullptr, xg, TPP*BB, 1536, 512);
    float* o = (l==2) ? out : nxt;
    gru_scan_mfma<<<dim3(32), dim3(512), 0, stream>>>(xg, Whh + (size_t)l*2*768*256,
                                                      bhh + (size_t)l*2*768, o);
    float* tmp = cur; cur = o; nxt = tmp;
  }
}